// Round 2
// baseline (119.080 us; speedup 1.0000x reference)
//
#include <hip/hip_runtime.h>

#define BS 16
#define S  256
#define H  1024
#define T  32
#define KSPLIT 4

// ws layout (floats):
//   pp[KSPLIT][4096][64]  partial GEMM results (cols 0..31 -> p1, 32..63 -> p2)
//   ps[BS*T]              seq @ W3^T + b
//   p1[4096*T]            reduced, ps folded in
//   p2[4096*T]            reduced
#define PP_OFF 0
#define PP_SZ  (KSPLIT * BS * S * 64)           // 1048576
#define PS_OFF (PP_OFF + PP_SZ)
#define P1_OFF (PS_OFF + 512)
#define P2_OFF (P1_OFF + BS * S * T)

// ---------------------------------------------------------------------------
// Kernel A: partial GEMM. blocks 0..1023: ks = blk>>8 (k-chunk of 256),
// mt = blk&255 (16-row tile). block 1024: ps.
// ---------------------------------------------------------------------------
__global__ __launch_bounds__(256) void gemm_partial(
    const float* __restrict__ seq, const float* __restrict__ E,
    const float* __restrict__ W, const float* __restrict__ bias,
    float* __restrict__ ws)
{
    const int tid = threadIdx.x;

    if (blockIdx.x == KSPLIT * 256) {
        // ---- ps[b,t] = seq[b,:] . W[t, 2H:3H] + bias[t] ----
        float* ps = ws + PS_OFF;
        #pragma unroll
        for (int rep = 0; rep < 2; ++rep) {
            int o = tid + rep * 256;           // 0..511
            int bb = o >> 5, t = o & 31;
            const float4* sp = (const float4*)(seq + (size_t)bb * H);
            const float4* wp = (const float4*)(W + (size_t)t * (3 * H) + 2 * H);
            float acc = 0.f;
            #pragma unroll 8
            for (int k = 0; k < H / 4; ++k) {
                float4 a = sp[k], w = wp[k];
                acc += a.x * w.x + a.y * w.y + a.z * w.z + a.w * w.w;
            }
            ps[o] = acc + bias[t];
        }
        return;
    }

    __shared__ __align__(16) float Et[16][68];   // pad: 2-way aliasing only (free)
    __shared__ __align__(16) float Wt[64][68];

    const int ks = blockIdx.x >> 8;
    const int m0 = (blockIdx.x & 255) * 16;
    const int kbeg = ks * (H / KSPLIT), kend = kbeg + H / KSPLIT;

    const int c2 = tid & 31;        // col c2 (p1 half), c2+32 (p2 half)
    const int rA = (tid >> 5) * 2, rB = rA + 1;
    const int srow = tid >> 4, sc4 = tid & 15;   // staging coords

    float a00 = 0.f, a01 = 0.f, a10 = 0.f, a11 = 0.f;
    float4 eReg, wReg[4];

    // register prefetch of tile at k0
    #define LOAD_REGS(k0)                                                      \
        {                                                                      \
            eReg = *(const float4*)(E + (size_t)(m0 + srow) * H + (k0) + sc4 * 4); \
            _Pragma("unroll")                                                  \
            for (int j = 0; j < 4; ++j) {                                      \
                int f = tid + j * 256, n = f >> 4, c4 = f & 15;                \
                const float* src = W + (size_t)(n & 31) * (3 * H)              \
                                     + ((n >> 5) ? H : 0) + (k0) + c4 * 4;     \
                wReg[j] = *(const float4*)src;                                 \
            }                                                                  \
        }

    LOAD_REGS(kbeg);

    for (int k0 = kbeg; k0 < kend; k0 += 64) {
        __syncthreads();                         // prior LDS reads done
        *(float4*)&Et[srow][sc4 * 4] = eReg;
        #pragma unroll
        for (int j = 0; j < 4; ++j) {
            int f = tid + j * 256, n = f >> 4, c4 = f & 15;
            *(float4*)&Wt[n][c4 * 4] = wReg[j];
        }
        __syncthreads();
        if (k0 + 64 < kend) LOAD_REGS(k0 + 64);  // hide next-tile latency under compute

        #pragma unroll
        for (int k4 = 0; k4 < 16; ++k4) {
            float4 ea = *(const float4*)&Et[rA][k4 * 4];
            float4 eb = *(const float4*)&Et[rB][k4 * 4];
            float4 wa = *(const float4*)&Wt[c2][k4 * 4];
            float4 wb = *(const float4*)&Wt[c2 + 32][k4 * 4];
            a00 += ea.x * wa.x + ea.y * wa.y + ea.z * wa.z + ea.w * wa.w;
            a01 += ea.x * wb.x + ea.y * wb.y + ea.z * wb.z + ea.w * wb.w;
            a10 += eb.x * wa.x + eb.y * wa.y + eb.z * wa.z + eb.w * wa.w;
            a11 += eb.x * wb.x + eb.y * wb.y + eb.z * wb.z + eb.w * wb.w;
        }
    }

    float* pp = ws + PP_OFF + (size_t)ks * (BS * S * 64);
    pp[(size_t)(m0 + rA) * 64 + c2]      = a00;
    pp[(size_t)(m0 + rA) * 64 + c2 + 32] = a01;
    pp[(size_t)(m0 + rB) * 64 + c2]      = a10;
    pp[(size_t)(m0 + rB) * 64 + c2 + 32] = a11;
}

// ---------------------------------------------------------------------------
// Kernel B: reduce KSPLIT partials; split cols into p1 (ps folded) and p2.
// 65536 threads, one float4 each.
// ---------------------------------------------------------------------------
__global__ __launch_bounds__(256) void reduce_p(float* __restrict__ ws)
{
    const int o = blockIdx.x * 256 + threadIdx.x;     // float4 index, 0..65535
    const float4* pp = (const float4*)(ws + PP_OFF);
    float4 v = pp[o];
    #pragma unroll
    for (int ks = 1; ks < KSPLIT; ++ks) {
        float4 u = pp[o + ks * (PP_SZ / KSPLIT / 4)];
        v.x += u.x; v.y += u.y; v.z += u.z; v.w += u.w;
    }
    const int row = o >> 4, c4 = o & 15;              // row 0..4095, 16 float4/row
    if (c4 < 8) {
        const int b = row >> 8;
        float4 s = ((const float4*)(ws + PS_OFF))[b * 8 + c4];
        v.x += s.x; v.y += s.y; v.z += s.z; v.w += s.w;
        ((float4*)(ws + P1_OFF))[row * 8 + c4] = v;
    } else {
        ((float4*)(ws + P2_OFF))[row * 8 + (c4 - 8)] = v;
    }
}

// ---------------------------------------------------------------------------
// Kernel C: out[b,i,j,t] = p1[b,i,t] + p2[b,j,t]   (ps already in p1)
// ---------------------------------------------------------------------------
__global__ __launch_bounds__(256) void bcast_add(
    const float* __restrict__ ws, float* __restrict__ out)
{
    const int blk = blockIdx.x;
    const int b = blk >> 8, i = blk & 255;
    const int tid = threadIdx.x;

    __shared__ __align__(16) float s1[32];
    if (tid < 32) s1[tid] = (ws + P1_OFF)[(size_t)(b * S + i) * T + tid];
    __syncthreads();

    const float4 s = *(const float4*)&s1[(tid & 7) * 4];
    const float4* p2v = (const float4*)(ws + P2_OFF) + (size_t)b * (S * T / 4);
    float4* ov = (float4*)out + (size_t)(b * S + i) * (S * T / 4);

    #pragma unroll
    for (int k = tid; k < S * T / 4; k += 256) {
        float4 v = p2v[k];
        float4 r;
        r.x = v.x + s.x; r.y = v.y + s.y; r.z = v.z + s.z; r.w = v.w + s.w;
        ov[k] = r;
    }
}

extern "C" void kernel_launch(void* const* d_in, const int* in_sizes, int n_in,
                              void* d_out, int out_size, void* d_ws, size_t ws_size,
                              hipStream_t stream)
{
    const float* seq  = (const float*)d_in[0];   // (16,1024)
    const float* E    = (const float*)d_in[1];   // (16,256,1024)
    const float* W    = (const float*)d_in[2];   // (32,3072)
    const float* bias = (const float*)d_in[3];   // (32,)
    float* out = (float*)d_out;                  // (16,256,256,32) f32
    float* ws  = (float*)d_ws;                   // ~5.3 MB used

    gemm_partial<<<KSPLIT * 256 + 1, 256, 0, stream>>>(seq, E, W, bias, ws);
    reduce_p<<<256, 256, 0, stream>>>(ws);
    bcast_add<<<BS * S, 256, 0, stream>>>(ws, out);
}

// Round 3
// 116.732 us; speedup vs baseline: 1.0201x; 1.0201x over previous
//
#include <hip/hip_runtime.h>

#define BS 16
#define S  256
#define H  1024
#define T  32
#define KSPLIT 4
#define MT 8          // rows per wave
#define KCH (H / KSPLIT)   // 256 k per wave

// ws layout (floats):
//   pp[KSPLIT][4096][64]  partial GEMM (cols 0..31 -> p1, 32..63 -> p2)
//   ps[BS*T], p1[4096*T] (ps folded), p2[4096*T]
#define PP_OFF 0
#define PP_SZ  (KSPLIT * BS * S * 64)           // 4 * 262144
#define PS_OFF (PP_OFF + PP_SZ)
#define P1_OFF (PS_OFF + 512)
#define P2_OFF (P1_OFF + BS * S * T)

// ---------------------------------------------------------------------------
// Kernel A: partial GEMM, wave-structured.
//   wave wid = blk*4 + (tid>>6); rg = wid>>2 (8-row group), ks = wid&3.
//   Lane n owns column n: W row in VGPRs (private), E tile broadcast from
//   this wave's own LDS region. No inner-loop barriers.
//   Block 512: ps[b,t] = seq[b,:] . W[t,2H:3H] + bias[t].
// ---------------------------------------------------------------------------
__global__ __launch_bounds__(256) void gemm_partial(
    const float* __restrict__ seq, const float* __restrict__ E,
    const float* __restrict__ W, const float* __restrict__ bias,
    float* __restrict__ ws)
{
    const int tid = threadIdx.x;

    if (blockIdx.x == 512) {
        float* ps = ws + PS_OFF;
        #pragma unroll
        for (int rep = 0; rep < 2; ++rep) {
            int o = tid + rep * 256;           // 0..511
            int bb = o >> 5, t = o & 31;
            const float4* sp = (const float4*)(seq + (size_t)bb * H);
            const float4* wp = (const float4*)(W + (size_t)t * (3 * H) + 2 * H);
            float acc = 0.f;
            #pragma unroll 8
            for (int k = 0; k < H / 4; ++k) {
                float4 a = sp[k], w = wp[k];
                acc += a.x * w.x + a.y * w.y + a.z * w.z + a.w * w.w;
            }
            ps[o] = acc + bias[t];
        }
        return;
    }

    __shared__ __align__(16) float Es[4][MT][KCH];   // 32 KB, one slab per wave

    const int wv = tid >> 6, lane = tid & 63;
    const int wid = blockIdx.x * 4 + wv;
    const int rg = wid >> 2;                   // 0..511, rows rg*8..rg*8+7
    const int ks = wid & 3;
    const int kbeg = ks * KCH;

    float* eb = &Es[wv][0][0];

    // ---- stage this wave's E tile: 8 rows x 256 k (8 KB), coalesced ----
    #pragma unroll
    for (int j = 0; j < MT; ++j) {
        float4 v = *(const float4*)(E + (size_t)(rg * MT + j) * H + kbeg + lane * 4);
        *(float4*)(eb + j * KCH + lane * 4) = v;
    }
    __syncthreads();   // only barrier; makes LDS writes visible for reads below

    // ---- lane-private W row: col n<32 -> W[n][0:H]; n>=32 -> W[n-32][H:2H] ----
    const int n = lane;
    const float* wb = W + (size_t)(n & 31) * (3 * H) + ((n >> 5) ? H : 0) + kbeg;

    float acc[MT] = {};

    #pragma unroll 2
    for (int kc = 0; kc < KCH / 16; ++kc) {          // 16 sub-chunks of 16 k
        const float4* wq = (const float4*)(wb + kc * 16);
        float4 w0 = wq[0], w1 = wq[1], w2 = wq[2], w3 = wq[3];
        #pragma unroll
        for (int m = 0; m < MT; ++m) {
            const float* er = eb + m * KCH + kc * 16;  // uniform addr -> broadcast
            float4 e0 = *(const float4*)(er);
            float4 e1 = *(const float4*)(er + 4);
            float4 e2 = *(const float4*)(er + 8);
            float4 e3 = *(const float4*)(er + 12);
            acc[m] += e0.x * w0.x + e0.y * w0.y + e0.z * w0.z + e0.w * w0.w
                    + e1.x * w1.x + e1.y * w1.y + e1.z * w1.z + e1.w * w1.w
                    + e2.x * w2.x + e2.y * w2.y + e2.z * w2.z + e2.w * w2.w
                    + e3.x * w3.x + e3.y * w3.y + e3.z * w3.z + e3.w * w3.w;
        }
    }

    // ---- store partials: lanes contiguous per m (256 B stores) ----
    float* pp = ws + PP_OFF + (size_t)ks * (BS * S * 64);
    #pragma unroll
    for (int m = 0; m < MT; ++m)
        pp[(size_t)(rg * MT + m) * 64 + n] = acc[m];
}

// ---------------------------------------------------------------------------
// Kernel B: reduce KSPLIT partials; split cols into p1 (ps folded) and p2.
// ---------------------------------------------------------------------------
__global__ __launch_bounds__(256) void reduce_p(float* __restrict__ ws)
{
    const int o = blockIdx.x * 256 + threadIdx.x;     // float4 idx, 0..65535
    const float4* pp = (const float4*)(ws + PP_OFF);
    float4 v = pp[o];
    #pragma unroll
    for (int ks = 1; ks < KSPLIT; ++ks) {
        float4 u = pp[o + ks * (PP_SZ / KSPLIT / 4)];
        v.x += u.x; v.y += u.y; v.z += u.z; v.w += u.w;
    }
    const int row = o >> 4, c4 = o & 15;              // row 0..4095
    if (c4 < 8) {
        const int b = row >> 8;
        float4 s = ((const float4*)(ws + PS_OFF))[b * 8 + c4];
        v.x += s.x; v.y += s.y; v.z += s.z; v.w += s.w;
        ((float4*)(ws + P1_OFF))[row * 8 + c4] = v;
    } else {
        ((float4*)(ws + P2_OFF))[row * 8 + (c4 - 8)] = v;
    }
}

// ---------------------------------------------------------------------------
// Kernel C: out[b,i,j,t] = p1[b,i,t] + p2[b,j,t]   (ps already in p1)
// ---------------------------------------------------------------------------
__global__ __launch_bounds__(256) void bcast_add(
    const float* __restrict__ ws, float* __restrict__ out)
{
    const int blk = blockIdx.x;
    const int b = blk >> 8, i = blk & 255;
    const int tid = threadIdx.x;

    __shared__ __align__(16) float s1[32];
    if (tid < 32) s1[tid] = (ws + P1_OFF)[(size_t)(b * S + i) * T + tid];
    __syncthreads();

    const float4 s = *(const float4*)&s1[(tid & 7) * 4];
    const float4* p2v = (const float4*)(ws + P2_OFF) + (size_t)b * (S * T / 4);
    float4* ov = (float4*)out + (size_t)(b * S + i) * (S * T / 4);

    #pragma unroll
    for (int k = tid; k < S * T / 4; k += 256) {
        float4 v = p2v[k];
        float4 r;
        r.x = v.x + s.x; r.y = v.y + s.y; r.z = v.z + s.z; r.w = v.w + s.w;
        ov[k] = r;
    }
}

extern "C" void kernel_launch(void* const* d_in, const int* in_sizes, int n_in,
                              void* d_out, int out_size, void* d_ws, size_t ws_size,
                              hipStream_t stream)
{
    const float* seq  = (const float*)d_in[0];   // (16,1024)
    const float* E    = (const float*)d_in[1];   // (16,256,1024)
    const float* W    = (const float*)d_in[2];   // (32,3072)
    const float* bias = (const float*)d_in[3];   // (32,)
    float* out = (float*)d_out;                  // (16,256,256,32) f32
    float* ws  = (float*)d_ws;                   // ~6.3 MB used

    gemm_partial<<<513, 256, 0, stream>>>(seq, E, W, bias, ws);
    reduce_p<<<256, 256, 0, stream>>>(ws);
    bcast_add<<<BS * S, 256, 0, stream>>>(ws, out);
}

// Round 4
// 106.398 us; speedup vs baseline: 1.1192x; 1.0971x over previous
//
#include <hip/hip_runtime.h>

#define BS 16
#define S  256
#define H  1024
#define T  32
#define KSPLIT 4
#define KCH (H / KSPLIT)    // 256 k per block
#define BM 32               // rows per block

// ws layout (floats):
//   pp[KSPLIT][4096][64]  partial GEMM (cols 0..31 -> p1, 32..63 -> p2)
//   ps[BS*T], p1[4096*T] (ps folded), p2[4096*T]
#define PP_OFF 0
#define PP_SZ  (KSPLIT * BS * S * 64)           // 1048576 floats
#define PS_OFF (PP_OFF + PP_SZ)
#define P1_OFF (PS_OFF + 512)
#define P2_OFF (P1_OFF + BS * S * T)

typedef __bf16 bf16x8 __attribute__((ext_vector_type(8)));
typedef float  f32x4  __attribute__((ext_vector_type(4)));

// ---------------------------------------------------------------------------
// Kernel A: MFMA partial GEMM. blk<512: ks=blk>>7 (k-chunk), mt=blk&127
// (32-row tile). 4 waves; wave w owns output cols [16w,16w+16).
// Block 512: ps[b,t] (f32, 4 ILP chains).
// ---------------------------------------------------------------------------
__global__ __launch_bounds__(256) void gemm_partial(
    const float* __restrict__ seq, const float* __restrict__ E,
    const float* __restrict__ W, const float* __restrict__ bias,
    float* __restrict__ ws)
{
    const int tid = threadIdx.x;

    if (blockIdx.x == 512) {
        float* ps = ws + PS_OFF;
        #pragma unroll
        for (int rep = 0; rep < 2; ++rep) {
            int o = tid + rep * 256;           // 0..511
            int bb = o >> 5, t = o & 31;
            const float4* sp = (const float4*)(seq + (size_t)bb * H);
            const float4* wp = (const float4*)(W + (size_t)t * (3 * H) + 2 * H);
            float a0 = 0.f, a1 = 0.f, a2 = 0.f, a3 = 0.f;   // 4 ILP chains
            #pragma unroll 2
            for (int k = 0; k < H / 4; k += 4) {
                float4 x0 = sp[k],     w0 = wp[k];
                float4 x1 = sp[k + 1], w1 = wp[k + 1];
                float4 x2 = sp[k + 2], w2 = wp[k + 2];
                float4 x3 = sp[k + 3], w3 = wp[k + 3];
                a0 += x0.x * w0.x + x0.y * w0.y + x0.z * w0.z + x0.w * w0.w;
                a1 += x1.x * w1.x + x1.y * w1.y + x1.z * w1.z + x1.w * w1.w;
                a2 += x2.x * w2.x + x2.y * w2.y + x2.z * w2.z + x2.w * w2.w;
                a3 += x3.x * w3.x + x3.y * w3.y + x3.z * w3.z + x3.w * w3.w;
            }
            ps[o] = a0 + a1 + a2 + a3 + bias[t];
        }
        return;
    }

    __shared__ __align__(16) float Ef[BM][KCH + 4];   // stride 260: 16B-aligned rows,
                                                      // <=2-way bank alias per pass
    const int lane = tid & 63, wv = tid >> 6;
    const int ks = blockIdx.x >> 7;
    const int m0 = (blockIdx.x & 127) * BM;
    const int kbeg = ks * KCH;

    // ---- wave-private B fragments: 16 W rows (f32, L2-hot) -> bf16 regs ----
    const int nb = wv * 16;
    const int wrow = nb + (lane & 15);                // output col 0..63
    const int ksub = (lane >> 4) * 8;                 // k sub-offset 0/8/16/24
    const float* wbase = W + (size_t)(wrow & 31) * (3 * H) + ((wrow >> 5) ? H : 0)
                           + kbeg + ksub;
    bf16x8 bfrag[8];
    #pragma unroll
    for (int s = 0; s < 8; ++s) {
        float4 lo = *(const float4*)(wbase + s * 32);
        float4 hi = *(const float4*)(wbase + s * 32 + 4);
        bf16x8 b;
        b[0] = (__bf16)lo.x; b[1] = (__bf16)lo.y; b[2] = (__bf16)lo.z; b[3] = (__bf16)lo.w;
        b[4] = (__bf16)hi.x; b[5] = (__bf16)hi.y; b[6] = (__bf16)hi.z; b[7] = (__bf16)hi.w;
        bfrag[s] = b;
    }

    // ---- stage E tile once: 32 rows x 256 k f32, coalesced 1KB/wave-instr ----
    #pragma unroll
    for (int i = 0; i < 8; ++i) {
        int f = tid + i * 256;                 // 0..2047
        int row = f >> 6, c4 = f & 63;
        float4 v = *(const float4*)(E + (size_t)(m0 + row) * H + kbeg + c4 * 4);
        *(float4*)&Ef[row][c4 * 4] = v;
    }
    __syncthreads();                           // the only barrier

    // ---- 16 MFMAs: 2 m-subtiles x 8 k-steps, acc accumulates over s ----
    f32x4 acc0 = {0.f, 0.f, 0.f, 0.f}, acc1 = {0.f, 0.f, 0.f, 0.f};
    const int erow = lane & 15;
    #pragma unroll
    for (int s = 0; s < 8; ++s) {
        const float* e0 = &Ef[erow][s * 32 + ksub];
        const float* e1 = &Ef[erow + 16][s * 32 + ksub];
        float4 p = *(const float4*)e0, q = *(const float4*)(e0 + 4);
        float4 r = *(const float4*)e1, u = *(const float4*)(e1 + 4);
        bf16x8 a0, a1;
        a0[0] = (__bf16)p.x; a0[1] = (__bf16)p.y; a0[2] = (__bf16)p.z; a0[3] = (__bf16)p.w;
        a0[4] = (__bf16)q.x; a0[5] = (__bf16)q.y; a0[6] = (__bf16)q.z; a0[7] = (__bf16)q.w;
        a1[0] = (__bf16)r.x; a1[1] = (__bf16)r.y; a1[2] = (__bf16)r.z; a1[3] = (__bf16)r.w;
        a1[4] = (__bf16)u.x; a1[5] = (__bf16)u.y; a1[6] = (__bf16)u.z; a1[7] = (__bf16)u.w;
        acc0 = __builtin_amdgcn_mfma_f32_16x16x32_bf16(a0, bfrag[s], acc0, 0, 0, 0);
        acc1 = __builtin_amdgcn_mfma_f32_16x16x32_bf16(a1, bfrag[s], acc1, 0, 0, 0);
    }

    // ---- store partials: D layout col=lane&15, row=(lane>>4)*4+r ----
    float* pp = ws + PP_OFF + (size_t)ks * (BS * S * 64);
    const int orow = (lane >> 4) * 4;
    const int ocol = nb + (lane & 15);
    #pragma unroll
    for (int r = 0; r < 4; ++r) {
        pp[(size_t)(m0 + orow + r) * 64 + ocol]      = acc0[r];
        pp[(size_t)(m0 + 16 + orow + r) * 64 + ocol] = acc1[r];
    }
}

// ---------------------------------------------------------------------------
// Kernel B: reduce KSPLIT partials; split cols into p1 (ps folded) and p2.
// ---------------------------------------------------------------------------
__global__ __launch_bounds__(256) void reduce_p(float* __restrict__ ws)
{
    const int o = blockIdx.x * 256 + threadIdx.x;     // float4 idx, 0..65535
    const float4* pp = (const float4*)(ws + PP_OFF);
    float4 v = pp[o];
    #pragma unroll
    for (int ks = 1; ks < KSPLIT; ++ks) {
        float4 u = pp[o + ks * (PP_SZ / KSPLIT / 4)];
        v.x += u.x; v.y += u.y; v.z += u.z; v.w += u.w;
    }
    const int row = o >> 4, c4 = o & 15;              // row 0..4095
    if (c4 < 8) {
        const int b = row >> 8;
        float4 s = ((const float4*)(ws + PS_OFF))[b * 8 + c4];
        v.x += s.x; v.y += s.y; v.z += s.z; v.w += s.w;
        ((float4*)(ws + P1_OFF))[row * 8 + c4] = v;
    } else {
        ((float4*)(ws + P2_OFF))[row * 8 + (c4 - 8)] = v;
    }
}

// ---------------------------------------------------------------------------
// Kernel C: out[b,i,j,t] = p1[b,i,t] + p2[b,j,t]   (ps already in p1)
// ---------------------------------------------------------------------------
__global__ __launch_bounds__(256) void bcast_add(
    const float* __restrict__ ws, float* __restrict__ out)
{
    const int blk = blockIdx.x;
    const int b = blk >> 8, i = blk & 255;
    const int tid = threadIdx.x;

    __shared__ __align__(16) float s1[32];
    if (tid < 32) s1[tid] = (ws + P1_OFF)[(size_t)(b * S + i) * T + tid];
    __syncthreads();

    const float4 s = *(const float4*)&s1[(tid & 7) * 4];
    const float4* p2v = (const float4*)(ws + P2_OFF) + (size_t)b * (S * T / 4);
    float4* ov = (float4*)out + (size_t)(b * S + i) * (S * T / 4);

    #pragma unroll
    for (int k = tid; k < S * T / 4; k += 256) {
        float4 v = p2v[k];
        float4 r;
        r.x = v.x + s.x; r.y = v.y + s.y; r.z = v.z + s.z; r.w = v.w + s.w;
        ov[k] = r;
    }
}

extern "C" void kernel_launch(void* const* d_in, const int* in_sizes, int n_in,
                              void* d_out, int out_size, void* d_ws, size_t ws_size,
                              hipStream_t stream)
{
    const float* seq  = (const float*)d_in[0];   // (16,1024)
    const float* E    = (const float*)d_in[1];   // (16,256,1024)
    const float* W    = (const float*)d_in[2];   // (32,3072)
    const float* bias = (const float*)d_in[3];   // (32,)
    float* out = (float*)d_out;                  // (16,256,256,32) f32
    float* ws  = (float*)d_ws;                   // ~5.3 MB used

    gemm_partial<<<513, 256, 0, stream>>>(seq, E, W, bias, ws);
    reduce_p<<<256, 256, 0, stream>>>(ws);
    bcast_add<<<BS * S, 256, 0, stream>>>(ws, out);
}

// Round 5
// 38.869 us; speedup vs baseline: 3.0636x; 2.7373x over previous
//
#include <hip/hip_runtime.h>

#define BS 16
#define S  256
#define H  1024
#define T  32
#define KSPLIT 4
#define KCH (H / KSPLIT)    // 256 k per block
#define BM 32               // rows per block

// ws layout (floats):
//   pp[KSPLIT][4096][64]  partial GEMM (cols 0..31 -> p1, 32..63 -> p2)
//   ps[BS*T], p1[4096*T] (ps folded), p2[4096*T]
#define PP_OFF 0
#define PP_SZ  (KSPLIT * BS * S * 64)           // 1048576 floats
#define PS_OFF (PP_OFF + PP_SZ)
#define P1_OFF (PS_OFF + 512)
#define P2_OFF (P1_OFF + BS * S * T)

typedef __bf16 bf16x8 __attribute__((ext_vector_type(8)));
typedef float  f32x4  __attribute__((ext_vector_type(4)));

// ---------------------------------------------------------------------------
// Kernel A: blk<512: MFMA partial GEMM (ks=blk>>7, 32-row tile blk&127).
//   blk in [512,640): ps — ONE WAVE per output (b,t), coalesced loads +
//   shfl_xor reduce. (R1-R4's single-block serial ps was an ~80us straggler
//   that set every dispatch's duration.)
// ---------------------------------------------------------------------------
__global__ __launch_bounds__(256) void gemm_partial(
    const float* __restrict__ seq, const float* __restrict__ E,
    const float* __restrict__ W, const float* __restrict__ bias,
    float* __restrict__ ws)
{
    const int tid = threadIdx.x;
    const int lane = tid & 63, wv = tid >> 6;

    if (blockIdx.x >= 512) {
        // ---- ps[b,t] = seq[b,:] . W[t,2H:3H] + bias[t], wave-parallel ----
        float* ps = ws + PS_OFF;
        const int o = (blockIdx.x - 512) * 4 + wv;    // 0..511
        const int bb = o >> 5, t = o & 31;
        const float4* sp = (const float4*)(seq + (size_t)bb * H) + lane * 4;
        const float4* wp = (const float4*)(W + (size_t)t * (3 * H) + 2 * H) + lane * 4;
        float acc = 0.f;
        #pragma unroll
        for (int k = 0; k < 4; ++k) {                 // lane covers 16 k-elems
            float4 a = sp[k], w = wp[k];
            acc += a.x * w.x + a.y * w.y + a.z * w.z + a.w * w.w;
        }
        #pragma unroll
        for (int m = 32; m >= 1; m >>= 1) acc += __shfl_xor(acc, m);
        if (lane == 0) ps[o] = acc + bias[t];
        return;
    }

    __shared__ __align__(16) float Ef[BM][KCH + 4];   // stride 260
    const int ks = blockIdx.x >> 7;
    const int m0 = (blockIdx.x & 127) * BM;
    const int kbeg = ks * KCH;

    // ---- wave-private B fragments: 16 W rows (f32, L2-hot) -> bf16 regs ----
    const int nb = wv * 16;
    const int wrow = nb + (lane & 15);                // output col 0..63
    const int ksub = (lane >> 4) * 8;                 // k sub-offset 0/8/16/24
    const float* wbase = W + (size_t)(wrow & 31) * (3 * H) + ((wrow >> 5) ? H : 0)
                           + kbeg + ksub;
    bf16x8 bfrag[8];
    #pragma unroll
    for (int s = 0; s < 8; ++s) {
        float4 lo = *(const float4*)(wbase + s * 32);
        float4 hi = *(const float4*)(wbase + s * 32 + 4);
        bf16x8 b;
        b[0] = (__bf16)lo.x; b[1] = (__bf16)lo.y; b[2] = (__bf16)lo.z; b[3] = (__bf16)lo.w;
        b[4] = (__bf16)hi.x; b[5] = (__bf16)hi.y; b[6] = (__bf16)hi.z; b[7] = (__bf16)hi.w;
        bfrag[s] = b;
    }

    // ---- stage E tile once: 32 rows x 256 k f32, coalesced ----
    #pragma unroll
    for (int i = 0; i < 8; ++i) {
        int f = tid + i * 256;                 // 0..2047
        int row = f >> 6, c4 = f & 63;
        float4 v = *(const float4*)(E + (size_t)(m0 + row) * H + kbeg + c4 * 4);
        *(float4*)&Ef[row][c4 * 4] = v;
    }
    __syncthreads();                           // the only barrier

    // ---- 16 MFMAs: 2 m-subtiles x 8 k-steps ----
    f32x4 acc0 = {0.f, 0.f, 0.f, 0.f}, acc1 = {0.f, 0.f, 0.f, 0.f};
    const int erow = lane & 15;
    #pragma unroll
    for (int s = 0; s < 8; ++s) {
        const float* e0 = &Ef[erow][s * 32 + ksub];
        const float* e1 = &Ef[erow + 16][s * 32 + ksub];
        float4 p = *(const float4*)e0, q = *(const float4*)(e0 + 4);
        float4 r = *(const float4*)e1, u = *(const float4*)(e1 + 4);
        bf16x8 a0, a1;
        a0[0] = (__bf16)p.x; a0[1] = (__bf16)p.y; a0[2] = (__bf16)p.z; a0[3] = (__bf16)p.w;
        a0[4] = (__bf16)q.x; a0[5] = (__bf16)q.y; a0[6] = (__bf16)q.z; a0[7] = (__bf16)q.w;
        a1[0] = (__bf16)r.x; a1[1] = (__bf16)r.y; a1[2] = (__bf16)r.z; a1[3] = (__bf16)r.w;
        a1[4] = (__bf16)u.x; a1[5] = (__bf16)u.y; a1[6] = (__bf16)u.z; a1[7] = (__bf16)u.w;
        acc0 = __builtin_amdgcn_mfma_f32_16x16x32_bf16(a0, bfrag[s], acc0, 0, 0, 0);
        acc1 = __builtin_amdgcn_mfma_f32_16x16x32_bf16(a1, bfrag[s], acc1, 0, 0, 0);
    }

    // ---- store partials: D layout col=lane&15, row=(lane>>4)*4+r ----
    float* pp = ws + PP_OFF + (size_t)ks * (BS * S * 64);
    const int orow = (lane >> 4) * 4;
    const int ocol = nb + (lane & 15);
    #pragma unroll
    for (int r = 0; r < 4; ++r) {
        pp[(size_t)(m0 + orow + r) * 64 + ocol]      = acc0[r];
        pp[(size_t)(m0 + 16 + orow + r) * 64 + ocol] = acc1[r];
    }
}

// ---------------------------------------------------------------------------
// Kernel B: reduce KSPLIT partials; split cols into p1 (ps folded) and p2.
// ---------------------------------------------------------------------------
__global__ __launch_bounds__(256) void reduce_p(float* __restrict__ ws)
{
    const int o = blockIdx.x * 256 + threadIdx.x;     // float4 idx, 0..65535
    const float4* pp = (const float4*)(ws + PP_OFF);
    float4 v = pp[o];
    #pragma unroll
    for (int ks = 1; ks < KSPLIT; ++ks) {
        float4 u = pp[o + ks * (PP_SZ / KSPLIT / 4)];
        v.x += u.x; v.y += u.y; v.z += u.z; v.w += u.w;
    }
    const int row = o >> 4, c4 = o & 15;              // row 0..4095
    if (c4 < 8) {
        const int b = row >> 8;
        float4 s = ((const float4*)(ws + PS_OFF))[b * 8 + c4];
        v.x += s.x; v.y += s.y; v.z += s.z; v.w += s.w;
        ((float4*)(ws + P1_OFF))[row * 8 + c4] = v;
    } else {
        ((float4*)(ws + P2_OFF))[row * 8 + (c4 - 8)] = v;
    }
}

// ---------------------------------------------------------------------------
// Kernel C: out[b,i,j,t] = p1[b,i,t] + p2[b,j,t]   (ps already in p1)
// ---------------------------------------------------------------------------
__global__ __launch_bounds__(256) void bcast_add(
    const float* __restrict__ ws, float* __restrict__ out)
{
    const int blk = blockIdx.x;
    const int b = blk >> 8, i = blk & 255;
    const int tid = threadIdx.x;

    __shared__ __align__(16) float s1[32];
    if (tid < 32) s1[tid] = (ws + P1_OFF)[(size_t)(b * S + i) * T + tid];
    __syncthreads();

    const float4 s = *(const float4*)&s1[(tid & 7) * 4];
    const float4* p2v = (const float4*)(ws + P2_OFF) + (size_t)b * (S * T / 4);
    float4* ov = (float4*)out + (size_t)(b * S + i) * (S * T / 4);

    #pragma unroll
    for (int k = tid; k < S * T / 4; k += 256) {
        float4 v = p2v[k];
        float4 r;
        r.x = v.x + s.x; r.y = v.y + s.y; r.z = v.z + s.z; r.w = v.w + s.w;
        ov[k] = r;
    }
}

extern "C" void kernel_launch(void* const* d_in, const int* in_sizes, int n_in,
                              void* d_out, int out_size, void* d_ws, size_t ws_size,
                              hipStream_t stream)
{
    const float* seq  = (const float*)d_in[0];   // (16,1024)
    const float* E    = (const float*)d_in[1];   // (16,256,1024)
    const float* W    = (const float*)d_in[2];   // (32,3072)
    const float* bias = (const float*)d_in[3];   // (32,)
    float* out = (float*)d_out;                  // (16,256,256,32) f32
    float* ws  = (float*)d_ws;                   // ~5.3 MB used

    gemm_partial<<<640, 256, 0, stream>>>(seq, E, W, bias, ws);
    reduce_p<<<256, 256, 0, stream>>>(ws);
    bcast_add<<<BS * S, 256, 0, stream>>>(ws, out);
}